// Round 9
// baseline (156.639 us; speedup 1.0000x reference)
//
#include <hip/hip_runtime.h>

// Problem constants (B=8, T=2048, C=1024, H=64)
#define TB 2048
#define NB 8
#define CEMB 1024
#define HD 64
#define BT (NB*TB)
// Q pre-scale: 1/sqrt(1024) * log2(e) — softmax in exp2 domain, no online max
#define QSCALE 0.04508422f

typedef __attribute__((ext_vector_type(8))) short bf16x8;
typedef __attribute__((ext_vector_type(4))) short bf16x4;
typedef __attribute__((ext_vector_type(4))) float f32x4;

#define MFMA32(a, b, c) __builtin_amdgcn_mfma_f32_16x16x32_bf16(a, b, c, 0, 0, 0)
// 16x16x16 bf16 MFMA: gfx90a-lineage builtin name, valid on gfx950.
// NOTE: no __has_builtin guard — it returns false on the HOST pass (R8 failure)
// even though the builtin parses fine in both passes.
#define MFMA16(a, b, c) __builtin_amdgcn_mfma_f32_16x16x16bf16_1k(a, b, c, 0, 0, 0)

__device__ inline short f2bf(float f) {
    union { float f; unsigned u; } v; v.f = f;
    unsigned r = v.u + 0x7fffu + ((v.u >> 16) & 1u);   // RNE
    return (short)(r >> 16);
}
__device__ inline float bf2f(short s) {
    union { unsigned u; float f; } v; v.u = ((unsigned)(unsigned short)s) << 16;
    return v.f;
}

// ---------- K1: pack [Wk;Wq;Wv] into MFMA B-frag order, bf16 ----------
__global__ __launch_bounds__(256) void wpack(const float* __restrict__ Wk,
                                             const float* __restrict__ Wq,
                                             const float* __restrict__ Wv,
                                             short* __restrict__ W2) {
    int c = blockIdx.x * 256 + threadIdx.x;          // 96 blocks
    int lane = c & 63, ntk = c >> 6;
    int nt = ntk % 12, kc = ntk / 12;
    int n = nt * 16 + (lane & 15);
    int col = kc * 32 + (lane >> 4) * 8;
    const float* src = (n < 64) ? Wk + n * 1024
                     : (n < 128) ? Wq + (n - 64) * 1024
                                 : Wv + (n - 128) * 1024;
    float4 a = *(const float4*)(src + col);
    float4 b = *(const float4*)(src + col + 4);
    bf16x8 o;
    o[0] = f2bf(a.x); o[1] = f2bf(a.y); o[2] = f2bf(a.z); o[3] = f2bf(a.w);
    o[4] = f2bf(b.x); o[5] = f2bf(b.y); o[6] = f2bf(b.z); o[7] = f2bf(b.w);
    *(bf16x8*)(W2 + (size_t)c * 8) = o;
}

// ---------- K2: QKV projection, K-split x4 across waves, W dbuf ----------
// All register arrays constant-indexed only (runtime index -> scratch, R3/R4).
__global__ __launch_bounds__(256) void qkv_proj(const float* __restrict__ x,
                                                const short* __restrict__ W2,
                                                short* __restrict__ Qb,
                                                short* __restrict__ Kb,
                                                short* __restrict__ Vt) {
    __shared__ short4 Lred[4][3][3][64];   // 18 KB bf16 partial exchange
    int tid = threadIdx.x, wave = tid >> 6, lane = tid & 63;
    int l15 = lane & 15, quad = lane >> 4;
    int m0 = blockIdx.x * 16;
    int mrow = m0 + l15;

    f32x4 acc[12];
#pragma unroll
    for (int i = 0; i < 12; ++i) acc[i] = f32x4{0.f, 0.f, 0.f, 0.f};

    const float4* xb4 = (const float4*)(x + (size_t)mrow * CEMB + wave * 256) + quad * 2;
    // 3-deep x pipeline (constant-indexed after unroll)
    float4 xq[6];
    xq[0] = xb4[0];  xq[1] = xb4[1];
    xq[2] = xb4[8];  xq[3] = xb4[9];
    xq[4] = xb4[16]; xq[5] = xb4[17];

    const short* wbase = W2 + ((size_t)(wave * 8) * 12 * 64 + lane) * 8;
    bf16x8 wA[12], wB[12];
#pragma unroll
    for (int nt = 0; nt < 12; ++nt)
        wA[nt] = *(const bf16x8*)(wbase + nt * 512);

#pragma unroll
    for (int kc = 0; kc < 8; ++kc) {
        float4 x0 = xq[(kc % 3) * 2], x1 = xq[(kc % 3) * 2 + 1];
        if (kc + 1 < 8) {
            const short* wn = wbase + (size_t)(kc + 1) * 6144;
            if (kc & 1) {
#pragma unroll
                for (int nt = 0; nt < 12; ++nt) wA[nt] = *(const bf16x8*)(wn + nt * 512);
            } else {
#pragma unroll
                for (int nt = 0; nt < 12; ++nt) wB[nt] = *(const bf16x8*)(wn + nt * 512);
            }
        }
        if (kc + 3 < 8) {
            xq[((kc + 3) % 3) * 2]     = xb4[(kc + 3) * 8];
            xq[((kc + 3) % 3) * 2 + 1] = xb4[(kc + 3) * 8 + 1];
        }
        bf16x8 af;
        af[0] = f2bf(x0.x); af[1] = f2bf(x0.y); af[2] = f2bf(x0.z); af[3] = f2bf(x0.w);
        af[4] = f2bf(x1.x); af[5] = f2bf(x1.y); af[6] = f2bf(x1.z); af[7] = f2bf(x1.w);
        if (kc & 1) {
#pragma unroll
            for (int nt = 0; nt < 12; ++nt) acc[nt] = MFMA32(af, wB[nt], acc[nt]);
        } else {
#pragma unroll
            for (int nt = 0; nt < 12; ++nt) acc[nt] = MFMA32(af, wA[nt], acc[nt]);
        }
    }

    // exchange partials in bf16 (each wave owns nt = 3*wave + {0,1,2})
#pragma unroll
    for (int nt = 0; nt < 12; ++nt) {
        int o = nt / 3;
        if (o != wave) {
            int rank = wave - (wave > o ? 1 : 0);
            short4 p;
            p.x = f2bf(acc[nt][0]); p.y = f2bf(acc[nt][1]);
            p.z = f2bf(acc[nt][2]); p.w = f2bf(acc[nt][3]);
            Lred[o][rank][nt % 3][lane] = p;
        }
    }
    __syncthreads();

    int b = blockIdx.x >> 7;
    int sblk = (m0 & 2047) >> 4;
#pragma unroll
    for (int nt = 0; nt < 12; ++nt) {
        if (wave == nt / 3) {              // wave-uniform, acc[nt] constant-indexed
            f32x4 s = acc[nt];
#pragma unroll
            for (int rk = 0; rk < 3; ++rk) {
                short4 p = Lred[nt / 3][rk][nt % 3][lane];
                s[0] += bf2f(p.x); s[1] += bf2f(p.y);
                s[2] += bf2f(p.z); s[3] += bf2f(p.w);
            }
            if (nt < 4) {                  // K rows [m][h]
                int h = nt * 16 + l15;
#pragma unroll
                for (int r = 0; r < 4; ++r)
                    Kb[(size_t)(m0 + quad * 4 + r) * HD + h] = f2bf(s[r]);
            } else if (nt < 8) {           // Q rows, pre-scaled
                int h = (nt - 4) * 16 + l15;
#pragma unroll
                for (int r = 0; r < 4; ++r)
                    Qb[(size_t)(m0 + quad * 4 + r) * HD + h] = f2bf(s[r] * QSCALE);
            } else {                       // V blocked [b][sblk][h][16]
                int h = (nt - 8) * 16 + l15;
                short4 o4;
                o4.x = f2bf(s[0]); o4.y = f2bf(s[1]); o4.z = f2bf(s[2]); o4.w = f2bf(s[3]);
                *(short4*)(Vt + ((size_t)(b * 128 + sblk) * 64 + h) * 16 + quad * 4) = o4;
            }
        }
    }
}

// ---------- K3: causal flash — transpose-free (S^T + 16x16x16 PV), no LDS loop ----------
__global__ __launch_bounds__(256) void flash(const short* __restrict__ Qb,
                                             const short* __restrict__ Kb,
                                             const short* __restrict__ Vt,
                                             float* __restrict__ out) {
    __shared__ float Of[4][16][68];        // merge only
    __shared__ float Ml[4][16];
    int tid = threadIdx.x, wave = tid >> 6, lane = tid & 63;
    int l15 = lane & 15, quad = lane >> 4;
    // CU-balance swizzle: CU c receives blocks {c, c+256, c+512, c+768}
    int i = blockIdx.x;
    int round = i >> 8, s = i & 255;
    int b = round * 2 + (s & 1);
    int q = (round & 1) ? 127 - (s >> 1) : (s >> 1);
    int tq0 = q * 16;
    size_t bT = (size_t)b * TB;

    const short* qrow = Qb + (bT + tq0 + l15) * HD;   // pre-scaled
    bf16x8 qf0 = *(const bf16x8*)(qrow + quad * 8);
    bf16x8 qf1 = *(const bf16x8*)(qrow + 32 + quad * 8);

    bf16x4 ones4;
#pragma unroll
    for (int j = 0; j < 4; ++j) ones4[j] = (short)0x3F80;   // bf16 1.0

    f32x4 accO[4];
#pragma unroll
    for (int k = 0; k < 4; ++k) accO[k] = f32x4{0.f, 0.f, 0.f, 0.f};
    f32x4 accL = f32x4{0.f, 0.f, 0.f, 0.f};

    int ntiles = (q + 4) >> 2;
    const short* kbase = Kb + bT * HD;
    const short* vtb = Vt + (size_t)b * 131072;       // [128 sblk][64 h][16 s]

    int myt = wave;
    if (myt < ntiles) {
        bf16x8 kf[8];
        {
            const short* kr = kbase + (size_t)(myt * 64 + l15) * HD + quad * 8;
#pragma unroll
            for (int st = 0; st < 4; ++st) {
                kf[st * 2]     = *(const bf16x8*)(kr + (size_t)st * 16 * HD);
                kf[st * 2 + 1] = *(const bf16x8*)(kr + (size_t)st * 16 * HD + 32);
            }
        }
        for (; myt < ntiles; myt += 4) {
            int s0 = myt * 64;
            // V^T A-frags for 16x16x16: lane m=h'=l15, k=s=quad*4+j (8B loads)
            bf16x4 vf[16];
#pragma unroll
            for (int g = 0; g < 4; ++g) {
                int sb = (s0 >> 4) + g;
#pragma unroll
                for (int ht = 0; ht < 4; ++ht)
                    vf[g * 4 + ht] = *(const bf16x4*)(vtb + ((size_t)(sb * 64 + ht * 16 + l15)) * 16 + quad * 4);
            }
            // S^T = mfma(A=K, B=Q): col=q=l15, row=s=quad*4+r
            f32x4 sv[4];
#pragma unroll
            for (int st = 0; st < 4; ++st) {
                f32x4 sacc = f32x4{0.f, 0.f, 0.f, 0.f};
                sacc = MFMA32(kf[st * 2], qf0, sacc);
                sacc = MFMA32(kf[st * 2 + 1], qf1, sacc);
                sv[st] = sacc;
            }
            // prefetch next K tile
            if (myt + 4 < ntiles) {
                const short* kr = kbase + (size_t)(s0 + 256 + l15) * HD + quad * 8;
#pragma unroll
                for (int st = 0; st < 4; ++st) {
                    kf[st * 2]     = *(const bf16x8*)(kr + (size_t)st * 16 * HD);
                    kf[st * 2 + 1] = *(const bf16x8*)(kr + (size_t)st * 16 * HD + 32);
                }
            }
            // mask + exp2 + pack into 16x16x16 B-frags (P^T) — all in registers
            bool full = (s0 + 64 <= tq0);
            int tg = tq0 + l15;
            bf16x4 pk[4];
#pragma unroll
            for (int st = 0; st < 4; ++st) {
#pragma unroll
                for (int r = 0; r < 4; ++r) {
                    int sg = s0 + st * 16 + quad * 4 + r;
                    float e = (full || sg <= tg) ? __builtin_amdgcn_exp2f(sv[st][r]) : 0.f;
                    pk[st][r] = f2bf(e);
                }
            }
            // O^T[h][q] += V^T x P^T ; rowsum via ones-A
#pragma unroll
            for (int g = 0; g < 4; ++g) {
                accL = MFMA16(ones4, pk[g], accL);
#pragma unroll
                for (int ht = 0; ht < 4; ++ht)
                    accO[ht] = MFMA16(vf[g * 4 + ht], pk[g], accO[ht]);
            }
        }
    }

    // ---- merge 4 partials: lane holds q=l15, regs are 4 contiguous h ----
#pragma unroll
    for (int ht = 0; ht < 4; ++ht) {
        float4 o4;
        o4.x = accO[ht][0]; o4.y = accO[ht][1]; o4.z = accO[ht][2]; o4.w = accO[ht][3];
        *(float4*)&Of[wave][l15][ht * 16 + quad * 4] = o4;
    }
    if (quad == 0) Ml[wave][l15] = accL[0];
    __syncthreads();

    int row = tid >> 4, c4 = (tid & 15) * 4;
    float L = Ml[0][row] + Ml[1][row] + Ml[2][row] + Ml[3][row];
    float inv = 1.0f / L;
    float4 p0 = *(const float4*)&Of[0][row][c4];
    float4 p1 = *(const float4*)&Of[1][row][c4];
    float4 p2 = *(const float4*)&Of[2][row][c4];
    float4 p3 = *(const float4*)&Of[3][row][c4];
    float4 o;
    o.x = (p0.x + p1.x + p2.x + p3.x) * inv;
    o.y = (p0.y + p1.y + p2.y + p3.y) * inv;
    o.z = (p0.z + p1.z + p2.z + p3.z) * inv;
    o.w = (p0.w + p1.w + p2.w + p3.w) * inv;
    *(float4*)(out + (bT + tq0 + row) * HD + c4) = o;
}

extern "C" void kernel_launch(void* const* d_in, const int* in_sizes, int n_in,
                              void* d_out, int out_size, void* d_ws, size_t ws_size,
                              hipStream_t stream) {
    const float* x  = (const float*)d_in[0];
    const float* Wk = (const float*)d_in[1];
    const float* Wq = (const float*)d_in[2];
    const float* Wv = (const float*)d_in[3];
    float* out = (float*)d_out;

    short* W2 = (short*)d_ws;                // 192*1024 bf16 (frag-packed)
    short* Qb = W2 + 192 * 1024;             // [BT][64], pre-scaled
    short* Kb = Qb + (size_t)BT * HD;        // [BT][64]
    short* Vt = Kb + (size_t)BT * HD;        // [B][128 sblk][64 h][16 s]

    wpack<<<96, 256, 0, stream>>>(Wk, Wq, Wv, W2);
    qkv_proj<<<1024, 256, 0, stream>>>(x, W2, Qb, Kb, Vt);
    flash<<<1024, 256, 0, stream>>>(Qb, Kb, Vt, out);
}

// Round 11
// 140.552 us; speedup vs baseline: 1.1145x; 1.1145x over previous
//
#include <hip/hip_runtime.h>

// Problem constants (B=8, T=2048, C=1024, H=64)
#define TB 2048
#define NB 8
#define CEMB 1024
#define HD 64
#define BT (NB*TB)
// Q pre-scale: 1/sqrt(1024) * log2(e) — softmax in exp2 domain, no online max
#define QSCALE 0.04508422f

typedef __attribute__((ext_vector_type(8))) short bf16x8;
typedef __attribute__((ext_vector_type(4))) short bf16x4;
typedef __attribute__((ext_vector_type(4))) float f32x4;

#define MFMA32(a, b, c) __builtin_amdgcn_mfma_f32_16x16x32_bf16(a, b, c, 0, 0, 0)
// no __has_builtin guard — returns false on the HOST pass (R8 failure)
#define MFMA16(a, b, c) __builtin_amdgcn_mfma_f32_16x16x16bf16_1k(a, b, c, 0, 0, 0)

__device__ inline short f2bf(float f) {
    union { float f; unsigned u; } v; v.f = f;
    unsigned r = v.u + 0x7fffu + ((v.u >> 16) & 1u);   // RNE
    return (short)(r >> 16);
}
__device__ inline float bf2f(short s) {
    union { unsigned u; float f; } v; v.u = ((unsigned)(unsigned short)s) << 16;
    return v.f;
}

// ---------- K1: pack [Wk;Wq;Wv] into MFMA B-frag order, bf16 ----------
__global__ __launch_bounds__(256) void wpack(const float* __restrict__ Wk,
                                             const float* __restrict__ Wq,
                                             const float* __restrict__ Wv,
                                             short* __restrict__ W2) {
    int c = blockIdx.x * 256 + threadIdx.x;          // 96 blocks
    int lane = c & 63, ntk = c >> 6;
    int nt = ntk % 12, kc = ntk / 12;
    int n = nt * 16 + (lane & 15);
    int col = kc * 32 + (lane >> 4) * 8;
    const float* src = (n < 64) ? Wk + n * 1024
                     : (n < 128) ? Wq + (n - 64) * 1024
                                 : Wv + (n - 128) * 1024;
    float4 a = *(const float4*)(src + col);
    float4 b = *(const float4*)(src + col + 4);
    bf16x8 o;
    o[0] = f2bf(a.x); o[1] = f2bf(a.y); o[2] = f2bf(a.z); o[3] = f2bf(a.w);
    o[4] = f2bf(b.x); o[5] = f2bf(b.y); o[6] = f2bf(b.z); o[7] = f2bf(b.w);
    *(bf16x8*)(W2 + (size_t)c * 8) = o;
}

// ---------- K2: QKV projection — 2 m-tiles/wave, K-split x4 ----------
// All register arrays constant-indexed only (runtime index -> scratch, R3/R4).
// 24 MFMAs per 12-frag load batch: 2x compute per L2 stall vs R9.
__global__ __launch_bounds__(256) void qkv_proj(const float* __restrict__ x,
                                                const short* __restrict__ W2,
                                                short* __restrict__ Qb,
                                                short* __restrict__ Kb,
                                                short* __restrict__ Vt) {
    __shared__ short4 Lred[4][3][6][64];   // 36 KB bf16 partial exchange
    int tid = threadIdx.x, wave = tid >> 6, lane = tid & 63;
    int l15 = lane & 15, quad = lane >> 4;
    int m0 = blockIdx.x * 32;              // grid 512

    f32x4 acc[24];                         // [nt*2 + mt]
#pragma unroll
    for (int i = 0; i < 24; ++i) acc[i] = f32x4{0.f, 0.f, 0.f, 0.f};

    const float4* xA = (const float4*)(x + (size_t)(m0 + l15) * CEMB + wave * 256) + quad * 2;
    const float4* xB = (const float4*)(x + (size_t)(m0 + 16 + l15) * CEMB + wave * 256) + quad * 2;
    // 2-deep x pipeline, constant-indexed after unroll
    float4 xq[8];
    xq[0] = xA[0]; xq[1] = xA[1]; xq[2] = xB[0]; xq[3] = xB[1];
    xq[4] = xA[8]; xq[5] = xA[9]; xq[6] = xB[8]; xq[7] = xB[9];

    const short* wbase = W2 + ((size_t)(wave * 8) * 12 * 64 + lane) * 8;
#pragma unroll
    for (int kc = 0; kc < 8; ++kc) {
        bf16x8 wf[12];
#pragma unroll
        for (int nt = 0; nt < 12; ++nt)    // batched frag loads
            wf[nt] = *(const bf16x8*)(wbase + (size_t)kc * 6144 + nt * 512);
        int base = (kc & 1) * 4;           // constant after unroll
        float4 a0 = xq[base], a1 = xq[base + 1];
        float4 b0 = xq[base + 2], b1 = xq[base + 3];
        if (kc + 2 < 8) {
            xq[base]     = xA[(kc + 2) * 8]; xq[base + 1] = xA[(kc + 2) * 8 + 1];
            xq[base + 2] = xB[(kc + 2) * 8]; xq[base + 3] = xB[(kc + 2) * 8 + 1];
        }
        bf16x8 af0, af1;
        af0[0] = f2bf(a0.x); af0[1] = f2bf(a0.y); af0[2] = f2bf(a0.z); af0[3] = f2bf(a0.w);
        af0[4] = f2bf(a1.x); af0[5] = f2bf(a1.y); af0[6] = f2bf(a1.z); af0[7] = f2bf(a1.w);
        af1[0] = f2bf(b0.x); af1[1] = f2bf(b0.y); af1[2] = f2bf(b0.z); af1[3] = f2bf(b0.w);
        af1[4] = f2bf(b1.x); af1[5] = f2bf(b1.y); af1[6] = f2bf(b1.z); af1[7] = f2bf(b1.w);
#pragma unroll
        for (int nt = 0; nt < 12; ++nt) {
            acc[nt * 2]     = MFMA32(af0, wf[nt], acc[nt * 2]);
            acc[nt * 2 + 1] = MFMA32(af1, wf[nt], acc[nt * 2 + 1]);
        }
    }

    // exchange partials in bf16 (wave owns nt = 3*wave + {0,1,2}, both mt)
#pragma unroll
    for (int nt = 0; nt < 12; ++nt) {
#pragma unroll
        for (int mt = 0; mt < 2; ++mt) {
            int o = nt / 3;
            if (o != wave) {
                int rank = wave - (wave > o ? 1 : 0);
                short4 p;
                p.x = f2bf(acc[nt * 2 + mt][0]); p.y = f2bf(acc[nt * 2 + mt][1]);
                p.z = f2bf(acc[nt * 2 + mt][2]); p.w = f2bf(acc[nt * 2 + mt][3]);
                Lred[o][rank][(nt % 3) * 2 + mt][lane] = p;
            }
        }
    }
    __syncthreads();

    int b = blockIdx.x >> 6;               // 64 blocks per batch
    int sblk32 = blockIdx.x & 63;
#pragma unroll
    for (int nt = 0; nt < 12; ++nt) {
        if (wave == nt / 3) {              // wave-uniform, constant acc index
            f32x4 s0 = acc[nt * 2], s1 = acc[nt * 2 + 1];
#pragma unroll
            for (int rk = 0; rk < 3; ++rk) {
                short4 p0 = Lred[nt / 3][rk][(nt % 3) * 2][lane];
                short4 p1 = Lred[nt / 3][rk][(nt % 3) * 2 + 1][lane];
                s0[0] += bf2f(p0.x); s0[1] += bf2f(p0.y); s0[2] += bf2f(p0.z); s0[3] += bf2f(p0.w);
                s1[0] += bf2f(p1.x); s1[1] += bf2f(p1.y); s1[2] += bf2f(p1.z); s1[3] += bf2f(p1.w);
            }
            if (nt < 4) {                  // K rows [m][h]
                int h = nt * 16 + l15;
#pragma unroll
                for (int r = 0; r < 4; ++r) {
                    Kb[(size_t)(m0 + quad * 4 + r) * HD + h]      = f2bf(s0[r]);
                    Kb[(size_t)(m0 + 16 + quad * 4 + r) * HD + h] = f2bf(s1[r]);
                }
            } else if (nt < 8) {           // Q rows, pre-scaled
                int h = (nt - 4) * 16 + l15;
#pragma unroll
                for (int r = 0; r < 4; ++r) {
                    Qb[(size_t)(m0 + quad * 4 + r) * HD + h]      = f2bf(s0[r] * QSCALE);
                    Qb[(size_t)(m0 + 16 + quad * 4 + r) * HD + h] = f2bf(s1[r] * QSCALE);
                }
            } else {                       // V: [b][s/32][h][32], pos = quad*8 + mt*4 + r
                int h = (nt - 8) * 16 + l15;
                bf16x8 v8;
                v8[0] = f2bf(s0[0]); v8[1] = f2bf(s0[1]); v8[2] = f2bf(s0[2]); v8[3] = f2bf(s0[3]);
                v8[4] = f2bf(s1[0]); v8[5] = f2bf(s1[1]); v8[6] = f2bf(s1[2]); v8[7] = f2bf(s1[3]);
                // h-stride is 32 shorts (R10 bug: was 16 -> colliding stores)
                *(bf16x8*)(Vt + ((size_t)((b * 64 + sblk32) * 64 + h)) * 32 + quad * 8) = v8;
            }
        }
    }
}

// ---------- K3: causal flash — 2 q-tiles/wave, transpose-free PV ----------
__global__ __launch_bounds__(256) void flash(const short* __restrict__ Qb,
                                             const short* __restrict__ Kb,
                                             const short* __restrict__ Vt,
                                             float* __restrict__ out) {
    __shared__ float Of[4][2][16][68];     // merge only (~35 KB)
    __shared__ float Ml[4][2][16];
    int tid = threadIdx.x, wave = tid >> 6, lane = tid & 63;
    int l15 = lane & 15, quad = lane >> 4;
    // CU-balance: CU c gets q32 = {g, 63-g} across the 2 rounds
    int i = blockIdx.x;                    // grid 512
    int round = i >> 8, s = i & 255;
    int b = s & 7;
    int g32 = s >> 3;
    int q32 = round ? 63 - g32 : g32;
    int tq0 = q32 * 32;
    size_t bT = (size_t)b * TB;

    const short* qr0 = Qb + (bT + tq0 + l15) * HD;        // pre-scaled
    const short* qr1 = Qb + (bT + tq0 + 16 + l15) * HD;
    bf16x8 qf00 = *(const bf16x8*)(qr0 + quad * 8);
    bf16x8 qf01 = *(const bf16x8*)(qr0 + 32 + quad * 8);
    bf16x8 qf10 = *(const bf16x8*)(qr1 + quad * 8);
    bf16x8 qf11 = *(const bf16x8*)(qr1 + 32 + quad * 8);

    bf16x4 ones4;
#pragma unroll
    for (int j = 0; j < 4; ++j) ones4[j] = (short)0x3F80;

    f32x4 accO0[4], accO1[4];
#pragma unroll
    for (int k = 0; k < 4; ++k) { accO0[k] = f32x4{0.f,0.f,0.f,0.f}; accO1[k] = f32x4{0.f,0.f,0.f,0.f}; }
    f32x4 accL0 = f32x4{0.f,0.f,0.f,0.f}, accL1 = f32x4{0.f,0.f,0.f,0.f};

    int ntiles = (tq0 + 95) >> 6;          // keys needed: tq0+32
    const short* kbase = Kb + bT * HD;
    const short* vtb = Vt + (size_t)b * 131072;  // [64 sblk32][64 h][32]

    int myt = wave;
    if (myt < ntiles) {
        bf16x8 kf[8];
        {
            const short* kr = kbase + (size_t)(myt * 64 + l15) * HD + quad * 8;
#pragma unroll
            for (int st = 0; st < 4; ++st) {
                kf[st * 2]     = *(const bf16x8*)(kr + (size_t)st * 16 * HD);
                kf[st * 2 + 1] = *(const bf16x8*)(kr + (size_t)st * 16 * HD + 32);
            }
        }
        for (; myt < ntiles; myt += 4) {
            int s0 = myt * 64;
            // V A-frags: one 16B load serves two 16-s groups (lo/hi halves)
            bf16x8 vf8[8];                 // [sb2*4 + ht]
#pragma unroll
            for (int sb2 = 0; sb2 < 2; ++sb2)
#pragma unroll
                for (int ht = 0; ht < 4; ++ht)
                    vf8[sb2 * 4 + ht] = *(const bf16x8*)(
                        vtb + ((size_t)(((s0 >> 5) + sb2) * 64 + ht * 16 + l15)) * 32 + quad * 8);
            // S^T = mfma(A=K, B=Q) for both q-tiles (K shared)
            f32x4 sv0[4], sv1[4];
#pragma unroll
            for (int st = 0; st < 4; ++st) {
                f32x4 t0 = f32x4{0.f,0.f,0.f,0.f}, t1 = f32x4{0.f,0.f,0.f,0.f};
                t0 = MFMA32(kf[st * 2], qf00, t0);
                t0 = MFMA32(kf[st * 2 + 1], qf01, t0);
                t1 = MFMA32(kf[st * 2], qf10, t1);
                t1 = MFMA32(kf[st * 2 + 1], qf11, t1);
                sv0[st] = t0; sv1[st] = t1;
            }
            // prefetch next K tile
            if (myt + 4 < ntiles) {
                const short* kr = kbase + (size_t)(s0 + 256 + l15) * HD + quad * 8;
#pragma unroll
                for (int st = 0; st < 4; ++st) {
                    kf[st * 2]     = *(const bf16x8*)(kr + (size_t)st * 16 * HD);
                    kf[st * 2 + 1] = *(const bf16x8*)(kr + (size_t)st * 16 * HD + 32);
                }
            }
            // mask + exp2 -> P^T B-frags for both q-tiles
            int t0g = tq0 + l15, t1g = tq0 + 16 + l15;
            bf16x4 pk0[4], pk1[4];
#pragma unroll
            for (int st = 0; st < 4; ++st) {
                bool full0 = (s0 + st * 16 + 15 <= tq0);
                bool full1 = (s0 + st * 16 + 15 <= tq0 + 16);
#pragma unroll
                for (int r = 0; r < 4; ++r) {
                    int sg = s0 + st * 16 + quad * 4 + r;
                    float e0 = (full0 || sg <= t0g) ? __builtin_amdgcn_exp2f(sv0[st][r]) : 0.f;
                    float e1 = (full1 || sg <= t1g) ? __builtin_amdgcn_exp2f(sv1[st][r]) : 0.f;
                    pk0[st][r] = f2bf(e0);
                    pk1[st][r] = f2bf(e1);
                }
            }
            // O^T += V^T x P^T (V shared); rowsum via ones-A
#pragma unroll
            for (int g = 0; g < 4; ++g) {
                accL0 = MFMA16(ones4, pk0[g], accL0);
                accL1 = MFMA16(ones4, pk1[g], accL1);
#pragma unroll
                for (int ht = 0; ht < 4; ++ht) {
                    bf16x8 v = vf8[(g >> 1) * 4 + ht];
                    bf16x4 va;
                    if (g & 1) { va[0] = v[4]; va[1] = v[5]; va[2] = v[6]; va[3] = v[7]; }
                    else       { va[0] = v[0]; va[1] = v[1]; va[2] = v[2]; va[3] = v[3]; }
                    accO0[ht] = MFMA16(va, pk0[g], accO0[ht]);
                    accO1[ht] = MFMA16(va, pk1[g], accO1[ht]);
                }
            }
        }
    }

    // ---- merge 4 partials per q-tile ----
#pragma unroll
    for (int ht = 0; ht < 4; ++ht) {
        float4 o0, o1;
        o0.x = accO0[ht][0]; o0.y = accO0[ht][1]; o0.z = accO0[ht][2]; o0.w = accO0[ht][3];
        o1.x = accO1[ht][0]; o1.y = accO1[ht][1]; o1.z = accO1[ht][2]; o1.w = accO1[ht][3];
        *(float4*)&Of[wave][0][l15][ht * 16 + quad * 4] = o0;
        *(float4*)&Of[wave][1][l15][ht * 16 + quad * 4] = o1;
    }
    if (quad == 0) { Ml[wave][0][l15] = accL0[0]; Ml[wave][1][l15] = accL1[0]; }
    __syncthreads();

    int row = tid >> 4, c4 = (tid & 15) * 4;
#pragma unroll
    for (int qt = 0; qt < 2; ++qt) {
        float L = Ml[0][qt][row] + Ml[1][qt][row] + Ml[2][qt][row] + Ml[3][qt][row];
        float inv = 1.0f / L;
        float4 p0 = *(const float4*)&Of[0][qt][row][c4];
        float4 p1 = *(const float4*)&Of[1][qt][row][c4];
        float4 p2 = *(const float4*)&Of[2][qt][row][c4];
        float4 p3 = *(const float4*)&Of[3][qt][row][c4];
        float4 o;
        o.x = (p0.x + p1.x + p2.x + p3.x) * inv;
        o.y = (p0.y + p1.y + p2.y + p3.y) * inv;
        o.z = (p0.z + p1.z + p2.z + p3.z) * inv;
        o.w = (p0.w + p1.w + p2.w + p3.w) * inv;
        *(float4*)(out + (bT + tq0 + qt * 16 + row) * HD + c4) = o;
    }
}

extern "C" void kernel_launch(void* const* d_in, const int* in_sizes, int n_in,
                              void* d_out, int out_size, void* d_ws, size_t ws_size,
                              hipStream_t stream) {
    const float* x  = (const float*)d_in[0];
    const float* Wk = (const float*)d_in[1];
    const float* Wq = (const float*)d_in[2];
    const float* Wv = (const float*)d_in[3];
    float* out = (float*)d_out;

    short* W2 = (short*)d_ws;                // 192*1024 bf16 (frag-packed)
    short* Qb = W2 + 192 * 1024;             // [BT][64], pre-scaled
    short* Kb = Qb + (size_t)BT * HD;        // [BT][64]
    short* Vt = Kb + (size_t)BT * HD;        // [B][64 sblk32][64 h][32]

    wpack<<<96, 256, 0, stream>>>(Wk, Wq, Wv, W2);
    qkv_proj<<<512, 256, 0, stream>>>(x, W2, Qb, Kb, Vt);
    flash<<<512, 256, 0, stream>>>(Qb, Kb, Vt, out);
}